// Round 2
// baseline (721.476 us; speedup 1.0000x reference)
//
#include <hip/hip_runtime.h>
#include <math.h>

#define N_NODES 100000
#define N_EDGES 3200000
#define SCAN_B 256
#define N_SCAN_BLOCKS ((N_NODES + SCAN_B - 1) / SCAN_B)   // 391

// ---------------- CSR-build kernels ----------------

__global__ void count_k(const int* __restrict__ dst, int* __restrict__ cnt) {
    int e = blockIdx.x * blockDim.x + threadIdx.x;
    if (e < N_EDGES) atomicAdd(&cnt[dst[e]], 1);
}

// per-block exclusive scan of cnt -> row_ptr (local), block totals -> bsum
__global__ void scan_local(const int* __restrict__ cnt, int* __restrict__ row_ptr,
                           int* __restrict__ bsum) {
    __shared__ int s[SCAN_B];
    int i = blockIdx.x * SCAN_B + threadIdx.x;
    int v = (i < N_NODES) ? cnt[i] : 0;
    s[threadIdx.x] = v;
    __syncthreads();
#pragma unroll
    for (int off = 1; off < SCAN_B; off <<= 1) {
        int t = (threadIdx.x >= off) ? s[threadIdx.x - off] : 0;
        __syncthreads();
        s[threadIdx.x] += t;
        __syncthreads();
    }
    if (i < N_NODES) row_ptr[i] = s[threadIdx.x] - v;   // exclusive
    if (threadIdx.x == SCAN_B - 1) bsum[blockIdx.x] = s[threadIdx.x];
}

// single-block scan of the 391 block sums -> exclusive block offsets (in place)
__global__ void scan_bsums(int* __restrict__ bsum) {
    __shared__ int s[512];
    int t = threadIdx.x;
    int v = (t < N_SCAN_BLOCKS) ? bsum[t] : 0;
    s[t] = v;
    __syncthreads();
#pragma unroll
    for (int off = 1; off < 512; off <<= 1) {
        int u = (t >= off) ? s[t - off] : 0;
        __syncthreads();
        s[t] += u;
        __syncthreads();
    }
    if (t < N_SCAN_BLOCKS) bsum[t] = s[t] - v;          // exclusive
}

// add block offsets; init cur = row_ptr; set row_ptr[N] = E (known statically)
__global__ void scan_add(int* __restrict__ row_ptr, const int* __restrict__ bsum,
                         int* __restrict__ cur) {
    int i = blockIdx.x * SCAN_B + threadIdx.x;
    if (i < N_NODES) {
        int v = row_ptr[i] + bsum[blockIdx.x];
        row_ptr[i] = v;
        cur[i] = v;
    }
    if (i == 0) row_ptr[N_NODES] = N_EDGES;
}

// bucket edges: permuted src + raw weight, grouped by dst
__global__ void fill_k(const int* __restrict__ src, const int* __restrict__ dst,
                       const float* __restrict__ w, int* __restrict__ cur,
                       int* __restrict__ ps, float* __restrict__ pw) {
    int e = blockIdx.x * blockDim.x + threadIdx.x;
    if (e >= N_EDGES) return;
    int d = dst[e];
    int p = atomicAdd(&cur[d], 1);
    ps[p] = src[e];
    pw[p] = w[e];
}

// weighted degree (incl. self-loop w=1) -> dinv
__global__ void deg_k(const int* __restrict__ row_ptr, const float* __restrict__ pw,
                      float* __restrict__ dinv) {
    int i = blockIdx.x * blockDim.x + threadIdx.x;
    if (i >= N_NODES) return;
    int j0 = row_ptr[i], j1 = row_ptr[i + 1];
    float s = 1.0f;                       // self-loop weight
    for (int j = j0; j < j1; j++) s += pw[j];
    dinv[i] = s > 0.0f ? rsqrtf(s) : 0.0f;
}

// fold symmetric norm into pw: pw[j] = dinv[dst] * w * dinv[src]
__global__ void norm_k(const int* __restrict__ row_ptr, const int* __restrict__ ps,
                       const float* __restrict__ dinv, float* __restrict__ pw) {
    int i = blockIdx.x * blockDim.x + threadIdx.x;
    if (i >= N_NODES) return;
    int j0 = row_ptr[i], j1 = row_ptr[i + 1];
    float di = dinv[i];
    for (int j = j0; j < j1; j++) pw[j] *= di * dinv[ps[j]];
}

// ---------------- dense / gather kernels ----------------

// h1 = x @ W1   ([N,64] @ [64,16]); 16 threads per node
__global__ void gemm1(const float* __restrict__ x, const float* __restrict__ W1,
                      float* __restrict__ h1) {
    __shared__ float sW[64 * 16];
    for (int t = threadIdx.x; t < 64 * 16; t += blockDim.x) sW[t] = W1[t];
    __syncthreads();
    int gid = blockIdx.x * blockDim.x + threadIdx.x;
    int node = gid >> 4, c = gid & 15;
    if (node >= N_NODES) return;
    const float* xr = x + node * 64;
    float acc = 0.0f;
#pragma unroll
    for (int k = 0; k < 64; k++) acc += xr[k] * sW[k * 16 + c];
    h1[node * 16 + c] = acc;
}

// conv1 aggregate by gather: 16 threads/node, register accumulation, fused relu+bias
__global__ void gather1(const int* __restrict__ row_ptr, const int* __restrict__ ps,
                        const float* __restrict__ pw, const float* __restrict__ dinv,
                        const float* __restrict__ h1, const float* __restrict__ b1,
                        float* __restrict__ h2) {
    int gid = blockIdx.x * blockDim.x + threadIdx.x;
    int node = gid >> 4, c = gid & 15;
    if (node >= N_NODES) return;
    float di = dinv[node];
    float acc = h1[node * 16 + c] * di * di + b1[c];   // self-loop + bias
    int j0 = row_ptr[node], j1 = row_ptr[node + 1];
    for (int j = j0; j < j1; j++) {
        acc += h1[ps[j] * 16 + c] * pw[j];
    }
    h2[node * 16 + c] = acc > 0.0f ? acc : 0.0f;
}

// x2pre = h2 @ W2   ([N,16] @ [16,2])
__global__ void gemm2(const float* __restrict__ h2, const float* __restrict__ W2,
                      float* __restrict__ x2pre) {
    __shared__ float sW[32];
    if (threadIdx.x < 32) sW[threadIdx.x] = W2[threadIdx.x];
    __syncthreads();
    int i = blockIdx.x * blockDim.x + threadIdx.x;
    if (i >= N_NODES) return;
    float a0 = 0.0f, a1 = 0.0f;
#pragma unroll
    for (int c = 0; c < 16; c++) {
        float v = h2[i * 16 + c];
        a0 += v * sW[c * 2];
        a1 += v * sW[c * 2 + 1];
    }
    x2pre[i * 2] = a0;
    x2pre[i * 2 + 1] = a1;
}

// conv2 gather + bias + relu + sigmoid head, fused final: one thread per node
__global__ void gather2(const int* __restrict__ row_ptr, const int* __restrict__ ps,
                        const float* __restrict__ pw, const float* __restrict__ dinv,
                        const float* __restrict__ x2pre, const float* __restrict__ b2,
                        const float* __restrict__ lin_w, const float* __restrict__ lin_b,
                        float* __restrict__ out) {
    int i = blockIdx.x * blockDim.x + threadIdx.x;
    if (i >= N_NODES) return;
    float di = dinv[i], di2 = di * di;
    float a0 = x2pre[i * 2] * di2;
    float a1 = x2pre[i * 2 + 1] * di2;
    int j0 = row_ptr[i], j1 = row_ptr[i + 1];
    for (int j = j0; j < j1; j++) {
        int s = ps[j];
        float wn = pw[j];
        a0 += x2pre[s * 2] * wn;
        a1 += x2pre[s * 2 + 1] * wn;
    }
    float x20 = a0 + b2[0];
    float x21 = a1 + b2[1];
    out[N_NODES + i * 2]     = x20;
    out[N_NODES + i * 2 + 1] = x21;
    float r0 = x20 > 0.0f ? x20 : 0.0f;
    float r1 = x21 > 0.0f ? x21 : 0.0f;
    float z = r0 * lin_w[0] + r1 * lin_w[1] + lin_b[0];
    out[i] = 1.0f / (1.0f + expf(-z));
}

extern "C" void kernel_launch(void* const* d_in, const int* in_sizes, int n_in,
                              void* d_out, int out_size, void* d_ws, size_t ws_size,
                              hipStream_t stream) {
    const float* x     = (const float*)d_in[0];
    const int*   ei    = (const int*)d_in[1];   // [2, E] flattened (int32 on device)
    const float* ew    = (const float*)d_in[2];
    const float* W1    = (const float*)d_in[3];
    const float* b1    = (const float*)d_in[4];
    const float* W2    = (const float*)d_in[5];
    const float* b2    = (const float*)d_in[6];
    const float* lin_w = (const float*)d_in[7];
    const float* lin_b = (const float*)d_in[8];
    float* out = (float*)d_out;

    const int* src = ei;
    const int* dst = ei + N_EDGES;

    // ---- workspace carve-up (byte offsets, 16B-aligned chunks) ----
    char* w8 = (char*)d_ws;
    size_t off = 0;
    auto take = [&](size_t bytes) { char* p = w8 + off; off += (bytes + 15) & ~((size_t)15); return (void*)p; };
    int*   cnt     = (int*)  take((size_t)N_NODES * 4);
    int*   row_ptr = (int*)  take((size_t)(N_NODES + 1) * 4);
    int*   cur     = (int*)  take((size_t)N_NODES * 4);
    int*   bsum    = (int*)  take(512 * 4);
    int*   ps      = (int*)  take((size_t)N_EDGES * 4);
    float* pw      = (float*)take((size_t)N_EDGES * 4);
    float* dinv    = (float*)take((size_t)N_NODES * 4);
    float* h1      = (float*)take((size_t)N_NODES * 16 * 4);
    float* h2      = (float*)take((size_t)N_NODES * 16 * 4);
    float* x2pre   = (float*)take((size_t)N_NODES * 2 * 4);

    const int B = 256;
    hipMemsetAsync(cnt, 0, (size_t)N_NODES * 4, stream);

    // CSR build
    count_k<<<(N_EDGES + B - 1) / B, B, 0, stream>>>(dst, cnt);
    scan_local<<<N_SCAN_BLOCKS, SCAN_B, 0, stream>>>(cnt, row_ptr, bsum);
    scan_bsums<<<1, 512, 0, stream>>>(bsum);
    scan_add<<<N_SCAN_BLOCKS, SCAN_B, 0, stream>>>(row_ptr, bsum, cur);
    fill_k<<<(N_EDGES + B - 1) / B, B, 0, stream>>>(src, dst, ew, cur, ps, pw);

    // degree + norm folding
    deg_k<<<(N_NODES + B - 1) / B, B, 0, stream>>>(row_ptr, pw, dinv);
    norm_k<<<(N_NODES + B - 1) / B, B, 0, stream>>>(row_ptr, ps, dinv, pw);

    // layer 1
    gemm1<<<(16 * N_NODES + B - 1) / B, B, 0, stream>>>(x, W1, h1);
    gather1<<<(16 * N_NODES + B - 1) / B, B, 0, stream>>>(row_ptr, ps, pw, dinv, h1, b1, h2);

    // layer 2 + head
    gemm2<<<(N_NODES + B - 1) / B, B, 0, stream>>>(h2, W2, x2pre);
    gather2<<<(N_NODES + B - 1) / B, B, 0, stream>>>(row_ptr, ps, pw, dinv, x2pre, b2,
                                                    lin_w, lin_b, out);
}

// Round 4
// 658.313 us; speedup vs baseline: 1.0959x; 1.0959x over previous
//
#include <hip/hip_runtime.h>
#include <math.h>

#define N_NODES 100000
#define N_EDGES 3200000
#define SCAN_B 256
#define N_SCAN_BLOCKS ((N_NODES + SCAN_B - 1) / SCAN_B)   // 391

typedef unsigned long long u64;

// ---------------- CSR-build kernels ----------------

// count incoming edges AND weighted degree per dst
__global__ void count_k(const int* __restrict__ dst, const float* __restrict__ w,
                        int* __restrict__ cnt, float* __restrict__ deg) {
    int e = blockIdx.x * blockDim.x + threadIdx.x;
    if (e >= N_EDGES) return;
    int d = dst[e];
    atomicAdd(&cnt[d], 1);
    atomicAdd(&deg[d], w[e]);
}

// per-block exclusive scan of cnt -> row_ptr (local), block totals -> bsum
__global__ void scan_local(const int* __restrict__ cnt, int* __restrict__ row_ptr,
                           int* __restrict__ bsum) {
    __shared__ int s[SCAN_B];
    int i = blockIdx.x * SCAN_B + threadIdx.x;
    int v = (i < N_NODES) ? cnt[i] : 0;
    s[threadIdx.x] = v;
    __syncthreads();
#pragma unroll
    for (int off = 1; off < SCAN_B; off <<= 1) {
        int t = (threadIdx.x >= off) ? s[threadIdx.x - off] : 0;
        __syncthreads();
        s[threadIdx.x] += t;
        __syncthreads();
    }
    if (i < N_NODES) row_ptr[i] = s[threadIdx.x] - v;   // exclusive
    if (threadIdx.x == SCAN_B - 1) bsum[blockIdx.x] = s[threadIdx.x];
}

// single-block scan of the 391 block sums -> exclusive block offsets (in place)
__global__ void scan_bsums(int* __restrict__ bsum) {
    __shared__ int s[512];
    int t = threadIdx.x;
    int v = (t < N_SCAN_BLOCKS) ? bsum[t] : 0;
    s[t] = v;
    __syncthreads();
#pragma unroll
    for (int off = 1; off < 512; off <<= 1) {
        int u = (t >= off) ? s[t - off] : 0;
        __syncthreads();
        s[t] += u;
        __syncthreads();
    }
    if (t < N_SCAN_BLOCKS) bsum[t] = s[t] - v;          // exclusive
}

// add block offsets; init cur; fused dinv = rsqrt(1 + weighted_deg)
__global__ void scan_add(int* __restrict__ row_ptr, const int* __restrict__ bsum,
                         int* __restrict__ cur, const float* __restrict__ deg,
                         float* __restrict__ dinv) {
    int i = blockIdx.x * SCAN_B + threadIdx.x;
    if (i < N_NODES) {
        int v = row_ptr[i] + bsum[blockIdx.x];
        row_ptr[i] = v;
        cur[i] = v;
        dinv[i] = rsqrtf(1.0f + deg[i]);   // self-loop weight 1; always > 0
    }
    if (i == 0) row_ptr[N_NODES] = N_EDGES;
}

// bucket edges grouped by dst: ONE 8B store of packed (src, normalized weight)
__global__ void fill_k(const int* __restrict__ src, const int* __restrict__ dst,
                       const float* __restrict__ w, const float* __restrict__ dinv,
                       int* __restrict__ cur, u64* __restrict__ pedge) {
    int e = blockIdx.x * blockDim.x + threadIdx.x;
    if (e >= N_EDGES) return;
    int s = src[e], d = dst[e];
    float wn = dinv[s] * w[e] * dinv[d];
    int p = atomicAdd(&cur[d], 1);
    pedge[p] = ((u64)(unsigned)s << 32) | (u64)__float_as_uint(wn);
}

// ---------------- dense / gather kernels ----------------

// h1 = x @ W1   ([N,64] @ [64,16]); 16 threads per node
__global__ void gemm1(const float* __restrict__ x, const float* __restrict__ W1,
                      float* __restrict__ h1) {
    __shared__ float sW[64 * 16];
    for (int t = threadIdx.x; t < 64 * 16; t += blockDim.x) sW[t] = W1[t];
    __syncthreads();
    int gid = blockIdx.x * blockDim.x + threadIdx.x;
    int node = gid >> 4, c = gid & 15;
    if (node >= N_NODES) return;
    const float* xr = x + node * 64;
    float acc = 0.0f;
#pragma unroll
    for (int k = 0; k < 64; k++) acc += xr[k] * sW[k * 16 + c];
    h1[node * 16 + c] = acc;
}

// conv1 gather + bias + relu, FUSED with gemm2 (16-lane butterfly reduce -> x2pre)
__global__ void gather1(const int* __restrict__ row_ptr, const u64* __restrict__ pedge,
                        const float* __restrict__ dinv, const float* __restrict__ h1,
                        const float* __restrict__ b1, const float* __restrict__ W2,
                        float* __restrict__ x2pre) {
    int gid = blockIdx.x * blockDim.x + threadIdx.x;
    int node = gid >> 4, c = gid & 15;
    if (node >= N_NODES) return;
    float di = dinv[node];
    float acc = h1[node * 16 + c] * di * di + b1[c];   // self-loop + bias
    int j0 = row_ptr[node], j1 = row_ptr[node + 1];
    for (int j = j0; j < j1; j++) {
        u64 pe = pedge[j];
        int s = (int)(pe >> 32);
        float wn = __uint_as_float((unsigned)pe);
        acc += h1[s * 16 + c] * wn;
    }
    float v = acc > 0.0f ? acc : 0.0f;                 // h2 value, kept in-register
    // fused gemm2: x2pre[node][k] = sum_c v_c * W2[c][k]
    float p0 = v * W2[c * 2];
    float p1 = v * W2[c * 2 + 1];
#pragma unroll
    for (int off = 8; off >= 1; off >>= 1) {
        p0 += __shfl_xor(p0, off, 16);
        p1 += __shfl_xor(p1, off, 16);
    }
    if (c == 0) {
        x2pre[node * 2]     = p0;
        x2pre[node * 2 + 1] = p1;
    }
}

// conv2 gather (8 lanes/node, butterfly reduce) + bias + relu + sigmoid head
__global__ void gather2(const int* __restrict__ row_ptr, const u64* __restrict__ pedge,
                        const float* __restrict__ dinv, const float* __restrict__ x2pre,
                        const float* __restrict__ b2, const float* __restrict__ lin_w,
                        const float* __restrict__ lin_b, float* __restrict__ out) {
    int gid = blockIdx.x * blockDim.x + threadIdx.x;
    int i = gid >> 3, l = gid & 7;
    if (i >= N_NODES) return;
    int j0 = row_ptr[i], j1 = row_ptr[i + 1];
    float a0 = 0.0f, a1 = 0.0f;
    for (int j = j0 + l; j < j1; j += 8) {
        u64 pe = pedge[j];
        int s = (int)(pe >> 32);
        float wn = __uint_as_float((unsigned)pe);
        const float2 xs = *(const float2*)(x2pre + s * 2);
        a0 += xs.x * wn;
        a1 += xs.y * wn;
    }
#pragma unroll
    for (int off = 4; off >= 1; off >>= 1) {
        a0 += __shfl_xor(a0, off, 8);
        a1 += __shfl_xor(a1, off, 8);
    }
    if (l == 0) {
        float di = dinv[i], di2 = di * di;
        const float2 xi = *(const float2*)(x2pre + i * 2);
        float x20 = a0 + xi.x * di2 + b2[0];
        float x21 = a1 + xi.y * di2 + b2[1];
        out[N_NODES + i * 2]     = x20;
        out[N_NODES + i * 2 + 1] = x21;
        float r0 = x20 > 0.0f ? x20 : 0.0f;
        float r1 = x21 > 0.0f ? x21 : 0.0f;
        float z = r0 * lin_w[0] + r1 * lin_w[1] + lin_b[0];
        out[i] = 1.0f / (1.0f + expf(-z));
    }
}

extern "C" void kernel_launch(void* const* d_in, const int* in_sizes, int n_in,
                              void* d_out, int out_size, void* d_ws, size_t ws_size,
                              hipStream_t stream) {
    const float* x     = (const float*)d_in[0];
    const int*   ei    = (const int*)d_in[1];   // [2, E] flattened
    const float* ew    = (const float*)d_in[2];
    const float* W1    = (const float*)d_in[3];
    const float* b1    = (const float*)d_in[4];
    const float* W2    = (const float*)d_in[5];
    const float* b2    = (const float*)d_in[6];
    const float* lin_w = (const float*)d_in[7];
    const float* lin_b = (const float*)d_in[8];
    float* out = (float*)d_out;

    const int* src = ei;
    const int* dst = ei + N_EDGES;

    // ---- workspace carve-up ----
    char* w8 = (char*)d_ws;
    size_t off = 0;
    auto take = [&](size_t bytes) { char* p = w8 + off; off += (bytes + 15) & ~((size_t)15); return (void*)p; };
    int*   cnt     = (int*)  take((size_t)N_NODES * 4);       // must be adjacent to deg
    float* deg     = (float*)take((size_t)N_NODES * 4);
    int*   row_ptr = (int*)  take((size_t)(N_NODES + 1) * 4);
    int*   cur     = (int*)  take((size_t)N_NODES * 4);
    int*   bsum    = (int*)  take(512 * 4);
    u64*   pedge   = (u64*)  take((size_t)N_EDGES * 8);
    float* dinv    = (float*)take((size_t)N_NODES * 4);
    float* h1      = (float*)take((size_t)N_NODES * 16 * 4);
    float* x2pre   = (float*)take((size_t)N_NODES * 2 * 4);

    const int B = 256;
    // zero cnt + deg in one memset (they are adjacent, both N*4 bytes, 16B-aligned)
    (void)hipMemsetAsync(cnt, 0, (size_t)2 * N_NODES * 4 + 16, stream);

    // CSR build (+ weighted degree via float atomics)
    count_k<<<(N_EDGES + B - 1) / B, B, 0, stream>>>(dst, ew, cnt, deg);
    scan_local<<<N_SCAN_BLOCKS, SCAN_B, 0, stream>>>(cnt, row_ptr, bsum);
    scan_bsums<<<1, 512, 0, stream>>>(bsum);
    scan_add<<<N_SCAN_BLOCKS, SCAN_B, 0, stream>>>(row_ptr, bsum, cur, deg, dinv);
    fill_k<<<(N_EDGES + B - 1) / B, B, 0, stream>>>(src, dst, ew, dinv, cur, pedge);

    // layer 1 (gemm1 independent of CSR build; gather1 fuses gemm2)
    gemm1<<<(16 * N_NODES + B - 1) / B, B, 0, stream>>>(x, W1, h1);
    gather1<<<(16 * N_NODES + B - 1) / B, B, 0, stream>>>(row_ptr, pedge, dinv, h1, b1, W2, x2pre);

    // layer 2 + head
    gather2<<<(8 * N_NODES + B - 1) / B, B, 0, stream>>>(row_ptr, pedge, dinv, x2pre, b2,
                                                        lin_w, lin_b, out);
}

// Round 5
// 420.175 us; speedup vs baseline: 1.7171x; 1.5668x over previous
//
#include <hip/hip_runtime.h>
#include <math.h>

#define N_NODES 100000
#define N_EDGES 3200000
#define SCAN_B 256
#define N_SCAN_BLOCKS ((N_NODES + SCAN_B - 1) / SCAN_B)   // 391

typedef unsigned long long u64;
typedef unsigned short u16;

// ---------------- CSR-build kernels ----------------

// one atomic per edge: within-bucket rank + final counts
__global__ void rank_k(const int* __restrict__ dst, int* __restrict__ cnt,
                       u16* __restrict__ rank) {
    int e = blockIdx.x * blockDim.x + threadIdx.x;
    if (e >= N_EDGES) return;
    int r = atomicAdd(&cnt[dst[e]], 1);
    rank[e] = (u16)r;   // max degree ~70 for this graph (Poisson lambda=32)
}

// per-block exclusive scan of cnt -> row_ptr (local), block totals -> bsum
__global__ void scan_local(const int* __restrict__ cnt, int* __restrict__ row_ptr,
                           int* __restrict__ bsum) {
    __shared__ int s[SCAN_B];
    int i = blockIdx.x * SCAN_B + threadIdx.x;
    int v = (i < N_NODES) ? cnt[i] : 0;
    s[threadIdx.x] = v;
    __syncthreads();
#pragma unroll
    for (int off = 1; off < SCAN_B; off <<= 1) {
        int t = (threadIdx.x >= off) ? s[threadIdx.x - off] : 0;
        __syncthreads();
        s[threadIdx.x] += t;
        __syncthreads();
    }
    if (i < N_NODES) row_ptr[i] = s[threadIdx.x] - v;   // exclusive
    if (threadIdx.x == SCAN_B - 1) bsum[blockIdx.x] = s[threadIdx.x];
}

// single-block scan of the 391 block sums -> exclusive block offsets (in place)
__global__ void scan_bsums(int* __restrict__ bsum) {
    __shared__ int s[512];
    int t = threadIdx.x;
    int v = (t < N_SCAN_BLOCKS) ? bsum[t] : 0;
    s[t] = v;
    __syncthreads();
#pragma unroll
    for (int off = 1; off < 512; off <<= 1) {
        int u = (t >= off) ? s[t - off] : 0;
        __syncthreads();
        s[t] += u;
        __syncthreads();
    }
    if (t < N_SCAN_BLOCKS) bsum[t] = s[t] - v;          // exclusive
}

// add block offsets -> final row_ptr
__global__ void scan_add(int* __restrict__ row_ptr, const int* __restrict__ bsum) {
    int i = blockIdx.x * SCAN_B + threadIdx.x;
    if (i < N_NODES) row_ptr[i] += bsum[blockIdx.x];
    if (i == 0) row_ptr[N_NODES] = N_EDGES;
}

// atomic-free scatter: pedge[row_ptr[d] + rank[e]] = (src, raw weight)
__global__ void scatter_k(const int* __restrict__ src, const int* __restrict__ dst,
                          const float* __restrict__ w, const u16* __restrict__ rank,
                          const int* __restrict__ row_ptr, u64* __restrict__ pedge) {
    int e = blockIdx.x * blockDim.x + threadIdx.x;
    if (e >= N_EDGES) return;
    int d = dst[e];
    int p = row_ptr[d] + (int)rank[e];
    pedge[p] = ((u64)(unsigned)src[e] << 32) | (u64)__float_as_uint(w[e]);
}

// weighted degree from CSR segments (8 lanes/node) -> dinv = rsqrt(1 + sum w)
__global__ void deg_k(const int* __restrict__ row_ptr, const u64* __restrict__ pedge,
                      float* __restrict__ dinv) {
    int gid = blockIdx.x * blockDim.x + threadIdx.x;
    int i = gid >> 3, l = gid & 7;
    if (i >= N_NODES) return;
    int j0 = row_ptr[i], j1 = row_ptr[i + 1];
    float s = 0.0f;
    for (int j = j0 + l; j < j1; j += 8) s += __uint_as_float((unsigned)pedge[j]);
#pragma unroll
    for (int off = 4; off >= 1; off >>= 1) s += __shfl_xor(s, off, 8);
    if (l == 0) dinv[i] = rsqrtf(1.0f + s);   // self-loop weight 1
}

// ---------------- dense / gather kernels ----------------

// g1 = (x @ W1) * dinv[node]   (pre-scaled by source-side norm factor)
__global__ void gemm1(const float* __restrict__ x, const float* __restrict__ W1,
                      const float* __restrict__ dinv, float* __restrict__ g1) {
    __shared__ float sW[64 * 16];
    for (int t = threadIdx.x; t < 64 * 16; t += blockDim.x) sW[t] = W1[t];
    __syncthreads();
    int gid = blockIdx.x * blockDim.x + threadIdx.x;
    int node = gid >> 4, c = gid & 15;
    if (node >= N_NODES) return;
    const float* xr = x + node * 64;
    float acc = 0.0f;
#pragma unroll
    for (int k = 0; k < 64; k++) acc += xr[k] * sW[k * 16 + c];
    g1[node * 16 + c] = acc * dinv[node];
}

// conv1 gather + bias + relu, fused gemm2; emits y2 = x2pre * dinv (pre-scaled)
// h2[c] = relu( (sum_j g1[s_j][c]*w_j + g1[node][c]) * dinv[node] + b1[c] )
__global__ void gather1(const int* __restrict__ row_ptr, const u64* __restrict__ pedge,
                        const float* __restrict__ dinv, const float* __restrict__ g1,
                        const float* __restrict__ b1, const float* __restrict__ W2,
                        float* __restrict__ y2) {
    int gid = blockIdx.x * blockDim.x + threadIdx.x;
    int node = gid >> 4, c = gid & 15;
    if (node >= N_NODES) return;
    float acc = g1[node * 16 + c];                     // self-loop (g1 = h1*dinv)
    int j0 = row_ptr[node], j1 = row_ptr[node + 1];
    for (int j = j0; j < j1; j++) {
        u64 pe = pedge[j];
        int s = (int)(pe >> 32);
        float wr = __uint_as_float((unsigned)pe);
        acc += g1[s * 16 + c] * wr;
    }
    float di = dinv[node];
    float v = acc * di + b1[c];
    v = v > 0.0f ? v : 0.0f;                           // h2, in-register
    // fused gemm2: x2pre[node][k] = sum_c v_c * W2[c][k]
    float p0 = v * W2[c * 2];
    float p1 = v * W2[c * 2 + 1];
#pragma unroll
    for (int off = 8; off >= 1; off >>= 1) {
        p0 += __shfl_xor(p0, off, 16);
        p1 += __shfl_xor(p1, off, 16);
    }
    if (c == 0) {
        y2[node * 2]     = p0 * di;                    // pre-scale for layer 2
        y2[node * 2 + 1] = p1 * di;
    }
}

// conv2 gather (8 lanes/node) + bias + relu + sigmoid head
// x2 = (sum_j y2[s_j]*w_j + y2[i]) * dinv[i] + b2
__global__ void gather2(const int* __restrict__ row_ptr, const u64* __restrict__ pedge,
                        const float* __restrict__ dinv, const float* __restrict__ y2,
                        const float* __restrict__ b2, const float* __restrict__ lin_w,
                        const float* __restrict__ lin_b, float* __restrict__ out) {
    int gid = blockIdx.x * blockDim.x + threadIdx.x;
    int i = gid >> 3, l = gid & 7;
    if (i >= N_NODES) return;
    int j0 = row_ptr[i], j1 = row_ptr[i + 1];
    float a0 = 0.0f, a1 = 0.0f;
    for (int j = j0 + l; j < j1; j += 8) {
        u64 pe = pedge[j];
        int s = (int)(pe >> 32);
        float wr = __uint_as_float((unsigned)pe);
        const float2 ys = *(const float2*)(y2 + s * 2);
        a0 += ys.x * wr;
        a1 += ys.y * wr;
    }
#pragma unroll
    for (int off = 4; off >= 1; off >>= 1) {
        a0 += __shfl_xor(a0, off, 8);
        a1 += __shfl_xor(a1, off, 8);
    }
    if (l == 0) {
        float di = dinv[i];
        const float2 yi = *(const float2*)(y2 + i * 2);
        float x20 = (a0 + yi.x) * di + b2[0];
        float x21 = (a1 + yi.y) * di + b2[1];
        out[N_NODES + i * 2]     = x20;
        out[N_NODES + i * 2 + 1] = x21;
        float r0 = x20 > 0.0f ? x20 : 0.0f;
        float r1 = x21 > 0.0f ? x21 : 0.0f;
        float z = r0 * lin_w[0] + r1 * lin_w[1] + lin_b[0];
        out[i] = 1.0f / (1.0f + expf(-z));
    }
}

extern "C" void kernel_launch(void* const* d_in, const int* in_sizes, int n_in,
                              void* d_out, int out_size, void* d_ws, size_t ws_size,
                              hipStream_t stream) {
    const float* x     = (const float*)d_in[0];
    const int*   ei    = (const int*)d_in[1];   // [2, E] flattened
    const float* ew    = (const float*)d_in[2];
    const float* W1    = (const float*)d_in[3];
    const float* b1    = (const float*)d_in[4];
    const float* W2    = (const float*)d_in[5];
    const float* b2    = (const float*)d_in[6];
    const float* lin_w = (const float*)d_in[7];
    const float* lin_b = (const float*)d_in[8];
    float* out = (float*)d_out;

    const int* src = ei;
    const int* dst = ei + N_EDGES;

    // ---- workspace carve-up ----
    char* w8 = (char*)d_ws;
    size_t off = 0;
    auto take = [&](size_t bytes) { char* p = w8 + off; off += (bytes + 15) & ~((size_t)15); return (void*)p; };
    int*   cnt     = (int*)  take((size_t)N_NODES * 4);
    int*   row_ptr = (int*)  take((size_t)(N_NODES + 1) * 4);
    int*   bsum    = (int*)  take(512 * 4);
    u16*   rank    = (u16*)  take((size_t)N_EDGES * 2);
    u64*   pedge   = (u64*)  take((size_t)N_EDGES * 8);
    float* dinv    = (float*)take((size_t)N_NODES * 4);
    float* g1      = (float*)take((size_t)N_NODES * 16 * 4);
    float* y2      = (float*)take((size_t)N_NODES * 2 * 4);

    const int B = 256;
    (void)hipMemsetAsync(cnt, 0, (size_t)N_NODES * 4, stream);

    // CSR build: one atomic per edge, then atomic-free scatter
    rank_k<<<(N_EDGES + B - 1) / B, B, 0, stream>>>(dst, cnt, rank);
    scan_local<<<N_SCAN_BLOCKS, SCAN_B, 0, stream>>>(cnt, row_ptr, bsum);
    scan_bsums<<<1, 512, 0, stream>>>(bsum);
    scan_add<<<N_SCAN_BLOCKS, SCAN_B, 0, stream>>>(row_ptr, bsum);
    scatter_k<<<(N_EDGES + B - 1) / B, B, 0, stream>>>(src, dst, ew, rank, row_ptr, pedge);

    // degree / norm factor from CSR (no atomics)
    deg_k<<<(8 * N_NODES + B - 1) / B, B, 0, stream>>>(row_ptr, pedge, dinv);

    // layer 1 (norm folded: g1 pre-scaled by dinv[src], gather scales by dinv[dst])
    gemm1<<<(16 * N_NODES + B - 1) / B, B, 0, stream>>>(x, W1, dinv, g1);
    gather1<<<(16 * N_NODES + B - 1) / B, B, 0, stream>>>(row_ptr, pedge, dinv, g1, b1, W2, y2);

    // layer 2 + head
    gather2<<<(8 * N_NODES + B - 1) / B, B, 0, stream>>>(row_ptr, pedge, dinv, y2, b2,
                                                        lin_w, lin_b, out);
}